// Round 5
// baseline (99.267 us; speedup 1.0000x reference)
//
#include <hip/hip_runtime.h>

// Inverse Haar wavelet 2D (fp32):
//   x:       [B=16, 4C=256, H=128, W=128]
//   filters: [4C,1,2,2] viewed as [C,4,2,2]
//   out:     [B, C=64, 256, 256]
// out[b][c][2h+p][2w+q] = sum_k x[b][4c+k][h][w] * f[c][k][p][q]
//
// Memory-bound streaming op: 268 MB in + 268 MB out, zero reuse.
// v2: fully-contiguous store instructions (one float4 per lane, 16B lane
// stride -> 1KB/instruction), float2 loads (512B/instruction/plane),
// grid-stride over batch with filters hoisted, non-temporal hints.

typedef float f32x2 __attribute__((ext_vector_type(2)));
typedef float f32x4 __attribute__((ext_vector_type(4)));

#define BB 16
#define CC 64
#define HH 128
#define WW 128
#define W2 (WW / 2)                 // 64 input-column pairs per row
#define SPATIAL (CC * HH * W2)      // 524288 threads: (c,h,w2), b looped

__global__ __launch_bounds__(256) void ihaar2d_kernel(
    const float* __restrict__ x,
    const float* __restrict__ filt,
    float* __restrict__ out)
{
    const int t  = blockIdx.x * 256 + threadIdx.x;  // exactly SPATIAL threads
    const int w2 = t & (W2 - 1);                    // 6 bits -> whole wave shares h
    const int h  = (t >> 6) & (HH - 1);             // 7 bits
    const int c  = t >> 13;                         // 0..63

    // Per-channel Haar taps, hoisted: f[k] = {p0q0, p0q1, p1q0, p1q1}
    const f32x4* f4 = (const f32x4*)(filt + c * 16);
    const f32x4 f0 = f4[0], f1 = f4[1], f2 = f4[2], f3 = f4[3];

    const int plane = HH * WW;
    const float* xb0 = x + ((c * 4) * HH + h) * WW + w2 * 2;
    float* ob0 = out + (c * (2 * HH) + 2 * h) * (2 * WW) + w2 * 4;

    const int x_bstride = 4 * CC * plane;            // per-batch input stride
    const int o_bstride = CC * (2 * HH) * (2 * WW);  // per-batch output stride

    for (int b = 0; b < BB; ++b) {
        const float* xb = xb0 + b * x_bstride;
        const f32x2 a0 = __builtin_nontemporal_load((const f32x2*)(xb + 0 * plane));
        const f32x2 a1 = __builtin_nontemporal_load((const f32x2*)(xb + 1 * plane));
        const f32x2 a2 = __builtin_nontemporal_load((const f32x2*)(xb + 2 * plane));
        const f32x2 a3 = __builtin_nontemporal_load((const f32x2*)(xb + 3 * plane));

        f32x4 r0, r1;   // output rows 2h and 2h+1, cols [4*w2, 4*w2+4)
        r0.x = a0.x * f0.x + a1.x * f1.x + a2.x * f2.x + a3.x * f3.x;
        r0.y = a0.x * f0.y + a1.x * f1.y + a2.x * f2.y + a3.x * f3.y;
        r0.z = a0.y * f0.x + a1.y * f1.x + a2.y * f2.x + a3.y * f3.x;
        r0.w = a0.y * f0.y + a1.y * f1.y + a2.y * f2.y + a3.y * f3.y;
        r1.x = a0.x * f0.z + a1.x * f1.z + a2.x * f2.z + a3.x * f3.z;
        r1.y = a0.x * f0.w + a1.x * f1.w + a2.x * f2.w + a3.x * f3.w;
        r1.z = a0.y * f0.z + a1.y * f1.z + a2.y * f2.z + a3.y * f3.z;
        r1.w = a0.y * f0.w + a1.y * f1.w + a2.y * f2.w + a3.y * f3.w;

        float* o = ob0 + b * o_bstride;
        __builtin_nontemporal_store(r0, (f32x4*)o);
        __builtin_nontemporal_store(r1, (f32x4*)(o + 2 * WW));
    }
}

extern "C" void kernel_launch(void* const* d_in, const int* in_sizes, int n_in,
                              void* d_out, int out_size, void* d_ws, size_t ws_size,
                              hipStream_t stream) {
    const float* x    = (const float*)d_in[0];
    const float* filt = (const float*)d_in[1];
    float* out        = (float*)d_out;

    const int threads = 256;
    const int blocks  = SPATIAL / threads;   // 2048 blocks = 8 per CU
    ihaar2d_kernel<<<blocks, threads, 0, stream>>>(x, filt, out);
}